// Round 7
// baseline (316.908 us; speedup 1.0000x reference)
//
#include <hip/hip_runtime.h>

// IrisSpecializedLoss — fused loss on MI355X (gfx950), round-7: LDS-staged
// (round-6 design, never ran due to GPU timeouts; + lr-hoist, + one fence).
// History: r2 115 µs @ VGPR=32, r5 110 µs @ VGPR=48 — both spilled the
// x[10][4] logits working set (WRITE_SIZE ~670KB vs ~85KB legit) and
// latency-serialized (HBM 18%, VALUBusy 16%). launch_bounds caps VGPRs but
// cannot stop the allocator targeting high occupancy and spilling.
// Fix: NO register working set. Per-block (=batch) the 10x900 f32 logits
// tile (36 KB) is staged to LDS via flat contiguous float4 loads (9
// independent chunks/thread, ~12 transient regs -> spill impossible);
// softmax/argmax then re-reads channels from LDS (ds_read_b128, lanes
// contiguous 16B -> optimal, ~12cyc ea vs 69 TB/s ceiling). 36.9 KB LDS ->
// 4 blocks/CU = 16 waves/CU of TLP.
//   ce      : m + log(sum exp(x-m)) - x_t   (two-pass over LDS tile)
//   exact   : argmax==t, strict > = first-max (JAX tie rule)
//   cons    : border-weighted eq sum (integer-exact)
//   colormap: sum(a^2) - 2 sum(a_t) + #px   (flat sweep + warm 4B gather)
//   rules   : 10-bit presence mask -> s-th set bit per slot (lr hoisted)
// Block partials -> ws -> deterministic double reduce (iris_finalize).

namespace {
constexpr int kB = 4096;
constexpr int kC = 10;
constexpr int kH = 30;
constexpr int kW = 30;
constexpr int kHW = kH * kW;      // 900
constexpr int kCHW = kC * kHW;    // 9000
constexpr int kThreads = 256;
constexpr int kP4 = kHW / 4;      // 225 pixel-quantum threads
constexpr int kF4 = kCHW / 4;     // 2250 float4s per batch (logits or att)
}  // namespace

__global__ __launch_bounds__(kThreads) void iris_main(
    const float* __restrict__ logits_g,   // [B,C,H,W]
    const int* __restrict__ targets_g,    // [B,H,W]
    const float* __restrict__ att_g,      // [B,H,W,C]
    const float* __restrict__ rules_g,    // [B,C]
    float* __restrict__ ce_part,          // [B]
    float* __restrict__ cm_part,          // [B] (sum a^2 - 2 sum a_t; +1/px in finalize)
    unsigned* __restrict__ weq_part,      // [B]
    unsigned* __restrict__ eq_part,       // [B]
    float* __restrict__ rule_part)        // [B]
{
    __shared__ float lds_x[kCHW];         // 36 KB: the batch's logits tile
    __shared__ float s_ce[4], s_cm[4];
    __shared__ unsigned s_weq[4], s_eq[4], s_mask[4];

    const int b = blockIdx.x;
    const int tid = threadIdx.x;
    const float* __restrict__ logits = logits_g + (size_t)b * kCHW;
    const int* __restrict__ tgt = targets_g + (size_t)b * kHW;
    const float* __restrict__ att = att_g + (size_t)b * kCHW;

    float ce_acc = 0.f, cm_acc = 0.f;
    unsigned weq_acc = 0u, eq_acc = 0u, mask_acc = 0u;

    const bool owner = (tid < kP4);
    const int p0 = tid * 4;

    // ---- 0. hoist the rules row (tid 0 only, 40B): drains under the body ----
    float lr[kC];
    if (tid == 0) {
#pragma unroll
        for (int c = 0; c < kC; c += 2) {
            const float2 v = *reinterpret_cast<const float2*>(rules_g + (size_t)b * kC + c);
            lr[c] = v.x; lr[c + 1] = v.y;
        }
    }

    // ---- 1. targets (gathers + masks depend on it) ----
    int ta[4] = {0, 0, 0, 0};
    if (owner) {
        const int4 tv = *reinterpret_cast<const int4*>(tgt + p0);
        ta[0] = tv.x; ta[1] = tv.y; ta[2] = tv.z; ta[3] = tv.w;
        mask_acc = (1u << ta[0]) | (1u << ta[1]) | (1u << ta[2]) | (1u << ta[3]);
    }

    // ---- 2. stage logits tile -> LDS: flat contiguous float4 stream,
    //         9 independent chunks/thread, tiny transient register need ----
#pragma unroll
    for (int k = 0; k < 8; ++k) {
        const int f4 = tid + kThreads * k;
        const float4 v = *reinterpret_cast<const float4*>(logits + 4 * f4);
        *reinterpret_cast<float4*>(lds_x + 4 * f4) = v;
    }
    if (tid < kF4 - 8 * kThreads) {       // tail: 202 float4s
        const int f4 = tid + kThreads * 8;
        const float4 v = *reinterpret_cast<const float4*>(logits + 4 * f4);
        *reinterpret_cast<float4*>(lds_x + 4 * f4) = v;
    }

    // ---- 3. a_t gathers (address dep on targets only; lines shared with
    //         the sweep below -> L1/L2 warm) ----
    float atg[4] = {0.f, 0.f, 0.f, 0.f};
    if (owner) {
#pragma unroll
        for (int j = 0; j < 4; ++j) atg[j] = att[(p0 + j) * kC + ta[j]];
    }
    __builtin_amdgcn_sched_barrier(0);  // keep staging+gather issue above the sweep

    // ---- 4. flat att sum-of-squares sweep (all 256 threads) ----
    {
        float sq = 0.f;
#pragma unroll
        for (int k = 0; k < 8; ++k) {
            const float4 v = *reinterpret_cast<const float4*>(att + 4 * (tid + kThreads * k));
            sq += v.x * v.x + v.y * v.y + v.z * v.z + v.w * v.w;
        }
        if (tid < kF4 - 8 * kThreads) {
            const float4 v = *reinterpret_cast<const float4*>(att + 4 * (tid + kThreads * 8));
            sq += v.x * v.x + v.y * v.y + v.z * v.z + v.w * v.w;
        }
        cm_acc = sq;
    }

    __syncthreads();   // staging complete; LDS tile readable

    if (owner) {
        cm_acc -= 2.f * (atg[0] + atg[1] + atg[2] + atg[3]);  // +1/px in finalize

        // ---- 5a. pass A: max / argmax / x_t from LDS (lanes read
        //          contiguous 16B within each 3600B plane: optimal) ----
        float xm[4], xt[4];
        int am[4];
#pragma unroll
        for (int j = 0; j < 4; ++j) { xm[j] = -3.4e38f; xt[j] = 0.f; am[j] = 0; }
#pragma unroll
        for (int c = 0; c < kC; ++c) {
            const float4 v = *reinterpret_cast<const float4*>(lds_x + c * kHW + p0);
            const float xv[4] = {v.x, v.y, v.z, v.w};
#pragma unroll
            for (int j = 0; j < 4; ++j) {
                const bool gt = xv[j] > xm[j];          // strict >: first max (JAX)
                am[j] = gt ? c : am[j];
                xm[j] = gt ? xv[j] : xm[j];
                xt[j] = (c == ta[j]) ? xv[j] : xt[j];   // compile-time c -> cndmask
            }
        }
        // ---- 5b. pass B: sum exp(x - m), re-read LDS (cheap) ----
        float s[4] = {0.f, 0.f, 0.f, 0.f};
#pragma unroll
        for (int c = 0; c < kC; ++c) {
            const float4 v = *reinterpret_cast<const float4*>(lds_x + c * kHW + p0);
            s[0] += __expf(v.x - xm[0]);
            s[1] += __expf(v.y - xm[1]);
            s[2] += __expf(v.z - xm[2]);
            s[3] += __expf(v.w - xm[3]);
        }
#pragma unroll
        for (int j = 0; j < 4; ++j) {
            ce_acc += xm[j] + __logf(s[j]) - xt[j];
            const unsigned eq = (am[j] == ta[j]) ? 1u : 0u;
            eq_acc += eq;
            const int p = p0 + j;
            const int h = p / kW;
            const int w = p - h * kW;
            const unsigned wgt = ((h == 0 || h == kH - 1) ? 1u : 2u) *
                                 ((w == 0 || w == kW - 1) ? 1u : 2u);
            weq_acc += eq * wgt;
        }
    }

    // ---- 6. wave reduce (64 lanes) ----
#pragma unroll
    for (int off = 32; off > 0; off >>= 1) {
        ce_acc  += __shfl_down(ce_acc, off);
        cm_acc  += __shfl_down(cm_acc, off);
        weq_acc += __shfl_down(weq_acc, off);
        eq_acc  += __shfl_down(eq_acc, off);
        mask_acc |= __shfl_down(mask_acc, off);
    }
    const int wave = tid >> 6;
    if ((tid & 63) == 0) {
        s_ce[wave] = ce_acc;
        s_cm[wave] = cm_acc;
        s_weq[wave] = weq_acc;
        s_eq[wave] = eq_acc;
        s_mask[wave] = mask_acc;
    }
    __syncthreads();

    if (tid == 0) {
        ce_part[b]  = s_ce[0] + s_ce[1] + s_ce[2] + s_ce[3];
        cm_part[b]  = s_cm[0] + s_cm[1] + s_cm[2] + s_cm[3];
        weq_part[b] = s_weq[0] + s_weq[1] + s_weq[2] + s_weq[3];
        eq_part[b]  = s_eq[0] + s_eq[1] + s_eq[2] + s_eq[3];
        const unsigned mask = s_mask[0] | s_mask[1] | s_mask[2] | s_mask[3];

        // rule target slot s = s-th smallest present color (else 0)
        unsigned mrem = mask;
        float rl = 0.f;
#pragma unroll
        for (int s2 = 0; s2 < kC; ++s2) {
            float v = 0.f;
            if (mrem) {
                v = (float)(__ffs(mrem) - 1);
                mrem &= mrem - 1u;
            }
            const float d = lr[s2] - v;
            rl += d * d;
        }
        rule_part[b] = rl;
    }
}

__global__ __launch_bounds__(1024) void iris_finalize(
    const float* __restrict__ ce_part,
    const float* __restrict__ cm_part,
    const unsigned* __restrict__ weq_part,
    const unsigned* __restrict__ eq_part,
    const float* __restrict__ rule_part,
    float* __restrict__ out)
{
    const int tid = threadIdx.x;
    double ce = 0.0, cm = 0.0, rl = 0.0;
    unsigned long long weq = 0ull, eqc = 0ull;
#pragma unroll
    for (int k = 0; k < 4; ++k) {
        const int i = tid + 1024 * k;
        ce += (double)ce_part[i];
        cm += (double)cm_part[i];
        rl += (double)rule_part[i];
        weq += (unsigned long long)weq_part[i];
        eqc += (unsigned long long)eq_part[i];
    }
#pragma unroll
    for (int off = 32; off > 0; off >>= 1) {
        ce  += __shfl_down(ce, off);
        cm  += __shfl_down(cm, off);
        rl  += __shfl_down(rl, off);
        weq += __shfl_down(weq, off);
        eqc += __shfl_down(eqc, off);
    }
    __shared__ double sd[3][16];
    __shared__ unsigned long long su[2][16];
    const int wave = tid >> 6;
    if ((tid & 63) == 0) {
        sd[0][wave] = ce; sd[1][wave] = cm; sd[2][wave] = rl;
        su[0][wave] = weq; su[1][wave] = eqc;
    }
    __syncthreads();
    if (tid == 0) {
        ce = 0.0; cm = 0.0; rl = 0.0; weq = 0ull; eqc = 0ull;
#pragma unroll
        for (int i = 0; i < 16; ++i) {
            ce += sd[0][i]; cm += sd[1][i]; rl += sd[2][i];
            weq += su[0][i]; eqc += su[1][i];
        }
        const double ce_m = ce / ((double)kB * kHW);
        // cm_part = sum a^2 - 2 sum a_t; add the +1-per-pixel constant here
        const double cm_m = (cm + (double)kB * kHW) / ((double)kB * kHW * kC);
        const double s_mean = (double)weq / ((double)kB * (kH - 1) * (kW - 1));
        const double cons = 1.0 - s_mean / 4.0;
        const double rl_m = rl / ((double)kB * kC);
        const double exact = (double)eqc;
        double total = ce_m + 0.4 * cm_m + 0.3 * cons + 0.2 * rl_m
                       - (exact / (double)kB) * 5.0;
        if (total < 0.001) total = 0.001;
        out[0] = (float)total;
        out[1] = (float)ce_m;
        out[2] = (float)cm_m;
        out[3] = (float)cons;
        out[4] = (float)rl_m;
        out[5] = (float)exact;
    }
}

extern "C" void kernel_launch(void* const* d_in, const int* in_sizes, int n_in,
                              void* d_out, int out_size, void* d_ws, size_t ws_size,
                              hipStream_t stream) {
    const float* color_output    = (const float*)d_in[0];
    const int*   targets         = (const int*)d_in[1];
    const float* color_attention = (const float*)d_in[2];
    const float* lstm_rules      = (const float*)d_in[3];
    float* out = (float*)d_out;

    // workspace layout: 5 arrays of kB entries (80 KB total)
    float*    ce_part   = (float*)d_ws;
    float*    cm_part   = ce_part + kB;
    unsigned* weq_part  = (unsigned*)(cm_part + kB);
    unsigned* eq_part   = weq_part + kB;
    float*    rule_part = (float*)(eq_part + kB);

    iris_main<<<kB, kThreads, 0, stream>>>(color_output, targets, color_attention,
                                           lstm_rules, ce_part, cm_part,
                                           weq_part, eq_part, rule_part);
    iris_finalize<<<1, 1024, 0, stream>>>(ce_part, cm_part, weq_part, eq_part,
                                          rule_part, out);
}